// Round 1
// baseline (96.112 us; speedup 1.0000x reference)
//
#include <hip/hip_runtime.h>

// TokenTreeModel: out[b,t,v] = bias + sum_{d,c: tok[b,t,d,c]==v} cnt[b,t,d,c]*w[d]
// B=2, T=256, DEPTH=8, VOCAB=32000, NCHILD=64
// out_size = 2*256*32000 = 16,384,000 fp32 (divisible by 4 -> float4 stores OK)

#define BB 2
#define TT 256
#define DEPTHD 8
#define VOCABV 32000
#define NCHILDC 64

// Kernel 1: fill entire output with bias (harness poisons d_out each call).
__global__ void tt_fill_bias(float* __restrict__ out,
                             const float* __restrict__ bias, int n4) {
    float b = bias[0];
    float4 v = make_float4(b, b, b, b);
    float4* __restrict__ o = reinterpret_cast<float4*>(out);
    int idx = blockIdx.x * blockDim.x + threadIdx.x;
    int stride = gridDim.x * blockDim.x;
    for (int i = idx; i < n4; i += stride) {
        o[i] = v;
    }
}

// Kernel 2: scatter-add count*w[d] into out[row, token].
// 262,144 entries total; collisions within a (b,t) row possible -> atomicAdd.
__global__ void tt_scatter_add(const int* __restrict__ tokens,
                               const float* __restrict__ counts,
                               const float* __restrict__ w,
                               float* __restrict__ out) {
    int i = blockIdx.x * blockDim.x + threadIdx.x;  // [0, B*T*DEPTH*NCHILD)
    int d   = (i >> 6) & 7;   // / NCHILD % DEPTH
    int row = i >> 9;         // / (DEPTH*NCHILD) -> b*T + t
    int tok = tokens[i];
    float val = counts[i] * w[d];
    atomicAdd(out + (long)row * VOCABV + tok, val);
}

extern "C" void kernel_launch(void* const* d_in, const int* in_sizes, int n_in,
                              void* d_out, int out_size, void* d_ws, size_t ws_size,
                              hipStream_t stream) {
    const int*   tokens = (const int*)d_in[0];
    const float* counts = (const float*)d_in[1];
    const float* w      = (const float*)d_in[2];
    const float* bias   = (const float*)d_in[3];
    float* out = (float*)d_out;

    int n4 = out_size / 4;  // 4,096,000 float4s
    tt_fill_bias<<<2048, 256, 0, stream>>>(out, bias, n4);

    int total = BB * TT * DEPTHD * NCHILDC;  // 262,144
    tt_scatter_add<<<total / 256, 256, 0, stream>>>(tokens, counts, w, out);
}

// Round 2
// 82.357 us; speedup vs baseline: 1.1670x; 1.1670x over previous
//
#include <hip/hip_runtime.h>

// TokenTreeModel: out[b,t,v] = bias + sum_{d,c: tok[b,t,d,c]==v} cnt[b,t,d,c]*w[d]
// B=2, T=256, DEPTH=8, VOCAB=32000, NCHILD=64
//
// Fused single-kernel design: one block per (row, vocab-half).
//   - LDS accumulator of 16000 floats (62.5 KiB) -> 2 blocks/CU
//   - zero LDS (float4), scatter 512 entries via LDS atomicAdd (filter by half),
//     stream out bias + acc with coalesced float4 stores.
// Global traffic = 65.5 MB write + ~4 MB read (ideal); no global atomics.

#define BB 2
#define TT 256
#define DEPTHD 8
#define VOCABV 32000
#define NCHILDC 64
#define HALF (VOCABV / 2)            // 16000
#define ENTRIES (DEPTHD * NCHILDC)   // 512 per row

__global__ __launch_bounds__(1024, 1) void tt_fused(
    const int* __restrict__ tokens,
    const float* __restrict__ counts,
    const float* __restrict__ w,
    const float* __restrict__ bias,
    float* __restrict__ out)
{
    __shared__ float acc[HALF];               // 64,000 B
    const int bid  = blockIdx.x;
    const int row  = bid >> 1;                // b*T + t
    const int half = bid & 1;                 // vocab half: [0,16000) or [16000,32000)
    const int tid  = threadIdx.x;

    // Phase 1: zero the LDS accumulator (float4 stores, 4000 x 16B).
    float4* acc4 = reinterpret_cast<float4*>(acc);
    #pragma unroll
    for (int i = tid; i < HALF / 4; i += 1024)
        acc4[i] = make_float4(0.f, 0.f, 0.f, 0.f);
    __syncthreads();

    // Phase 2: scatter this row's 512 (token, count) pairs into LDS.
    if (tid < ENTRIES) {
        const int idx = row * ENTRIES + tid;
        const int tok = tokens[idx];
        const float val = counts[idx] * w[(tid >> 6) & 7];  // d = tid/NCHILD
        const int local = tok - half * HALF;
        if ((unsigned)local < (unsigned)HALF)
            atomicAdd(&acc[local], val);
    }
    __syncthreads();

    // Phase 3: stream half-row to global with bias added (coalesced float4).
    const float b = bias[0];
    float4* o4 = reinterpret_cast<float4*>(out + (size_t)row * VOCABV + half * HALF);
    #pragma unroll
    for (int i = tid; i < HALF / 4; i += 1024) {
        float4 v = acc4[i];
        o4[i] = make_float4(v.x + b, v.y + b, v.z + b, v.w + b);
    }
}

extern "C" void kernel_launch(void* const* d_in, const int* in_sizes, int n_in,
                              void* d_out, int out_size, void* d_ws, size_t ws_size,
                              hipStream_t stream) {
    const int*   tokens = (const int*)d_in[0];
    const float* counts = (const float*)d_in[1];
    const float* w      = (const float*)d_in[2];
    const float* bias   = (const float*)d_in[3];
    float* out = (float*)d_out;

    const int nblocks = BB * TT * 2;  // 512 rows x 2 halves = 1024
    tt_fused<<<nblocks, 1024, 0, stream>>>(tokens, counts, w, bias, out);
}